// Round 7
// baseline (244.281 us; speedup 1.0000x reference)
//
#include <hip/hip_runtime.h>

// AlgebraicAttention on MI355X (gfx950), round 7.
// R6 post-mortem: gemm_qkv 66us = 391 TF, MfmaUtil 14% == pure-MFMA-time/dur ->
// ~80% barrier-drain stall (syncthreads' vmcnt(0) serializes the full load latency
// every K-iter; 3 lockstep blocks/CU give no cross-block overlap).
// Fix: double-buffered LDS K-loop with raw s_barrier + s_waitcnt vmcnt(8) (m139/AITER
// mechanism): tile k+1 issued before computing tile k, wait covers only tile k.
// Attention gets the same treatment via register prefetch of next chunk's K/V.
// ws: [0,8M) xb->Opart | [8,10M) wqb->Dpart | [10,12M) wkb | [12,14M) wvb |
//     [14,16M) wob | [16,24M) Qb (att in-place). d_out: [0,8M) Kb | [8,16M) Vtg.

typedef __attribute__((ext_vector_type(8))) __bf16 bf16x8;
typedef __attribute__((ext_vector_type(4))) __bf16 bf16x4;
typedef __attribute__((ext_vector_type(4))) float f32x4;
typedef unsigned short u16;

__device__ __forceinline__ u16 f2bf(float f) {
  unsigned u = __float_as_uint(f);
  u += 0x7FFFu + ((u >> 16) & 1u);   // round-to-nearest-even
  return (u16)(u >> 16);
}
__device__ __forceinline__ float bf2f(u16 b) {
  return __uint_as_float(((unsigned)b) << 16);
}
__device__ __forceinline__ void gl_lds16(const void* g, void* l) {
  __builtin_amdgcn_global_load_lds((__attribute__((address_space(1))) void*)g,
                                   (__attribute__((address_space(3))) void*)l,
                                   16, 0, 0);
}

// ---------------------------------------------------------------- cast kernel
__global__ __launch_bounds__(256) void cast_all_kernel(
    const float* __restrict__ x,  const float* __restrict__ wq,
    const float* __restrict__ wk, const float* __restrict__ wv,
    const float* __restrict__ wo,
    u16* __restrict__ xb, u16* __restrict__ wqb, u16* __restrict__ wkb,
    u16* __restrict__ wvb, u16* __restrict__ wob) {
  long i4 = (long)blockIdx.x * 256 + threadIdx.x;
  const float* src; u16* dst; long rel;
  if (i4 < 1048576) { src = x; dst = xb; rel = i4; }
  else {
    long j = i4 - 1048576;
    int w = (int)(j >> 18);
    rel = j & 262143;
    src = (w == 0) ? wq : (w == 1) ? wk : (w == 2) ? wv : wo;
    dst = (w == 0) ? wqb : (w == 1) ? wkb : (w == 2) ? wvb : wob;
  }
  float4 v = ((const float4*)src)[rel];
  ushort4 o;
  o.x = f2bf(v.x); o.y = f2bf(v.y); o.z = f2bf(v.z); o.w = f2bf(v.w);
  ((ushort4*)dst)[rel] = o;
}

// ---------------------------------------------------------------- pipelined GEMM body
// C = A @ B^T (+bias). 128x128 tile, BK=64, double-buffered LDS (64KB), software
// pipeline: issue gl_lds for tile kt+1, s_waitcnt vmcnt(8) (= only tile kt done),
// raw s_barrier, compute, raw s_barrier. Tile-k latency overlaps tile-(k-1) compute.
template <bool STORE_BF16>
__device__ __forceinline__ void gemm_body(
    const u16* __restrict__ A, const u16* __restrict__ B,
    const float* __restrict__ bias, bool rowbias,
    void* __restrict__ Cout, int ldc, int m0, int n0) {
  constexpr int K = 1024;
  constexpr int NT = K / 64;
  __shared__ __align__(16) u16 As[2][128 * 64];
  __shared__ __align__(16) u16 Bs[2][128 * 64];

  const int t = threadIdx.x;
  const int lane = t & 63;
  const int wv = t >> 6;
  const int quad = lane >> 4;
  const int l15 = lane & 15;
  const int wr = wv >> 1, wc = wv & 1;

  const f32x4 vzero = {0.f, 0.f, 0.f, 0.f};
  f32x4 acc[4][4];
#pragma unroll
  for (int i = 0; i < 4; ++i)
#pragma unroll
    for (int j = 0; j < 4; ++j) acc[i][j] = vzero;

  auto stage = [&](int kt, int bufi) {
#pragma unroll
    for (int p = 0; p < 4; ++p) {
      int idx = t + p * 256;
      int row = idx >> 3, seg = idx & 7;
      gl_lds16(&A[(long)(m0 + row) * K + kt * 64 + seg * 8], &As[bufi][idx * 8]);
      gl_lds16(&B[(long)(n0 + row) * K + kt * 64 + seg * 8], &Bs[bufi][idx * 8]);
    }
  };

  stage(0, 0);
  for (int kt = 0; kt < NT; ++kt) {
    const int bufi = kt & 1;
    if (kt + 1 < NT) {
      stage(kt + 1, bufi ^ 1);
      asm volatile("s_waitcnt vmcnt(8)" ::: "memory");   // tile kt resident
    } else {
      asm volatile("s_waitcnt vmcnt(0)" ::: "memory");
    }
    asm volatile("s_barrier" ::: "memory");              // all waves: tile kt ready
#pragma unroll
    for (int ks = 0; ks < 64; ks += 32) {
      bf16x8 af[4], bfg[4];
#pragma unroll
      for (int i = 0; i < 4; ++i)
        af[i] = *(const bf16x8*)&As[bufi][(wr * 64 + i * 16 + l15) * 64 + ks + quad * 8];
#pragma unroll
      for (int j = 0; j < 4; ++j)
        bfg[j] = *(const bf16x8*)&Bs[bufi][(wc * 64 + j * 16 + l15) * 64 + ks + quad * 8];
#pragma unroll
      for (int i = 0; i < 4; ++i)
#pragma unroll
        for (int j = 0; j < 4; ++j)
          acc[i][j] = __builtin_amdgcn_mfma_f32_16x16x32_bf16(af[i], bfg[j], acc[i][j], 0, 0, 0);
    }
    asm volatile("s_barrier" ::: "memory");  // reads(kt) done before writes(kt+2)
  }

  float cb[4];
  if (!rowbias) {
#pragma unroll
    for (int j = 0; j < 4; ++j) cb[j] = bias[n0 + wc * 64 + j * 16 + l15];
  }

#pragma unroll
  for (int i = 0; i < 4; ++i) {
#pragma unroll
    for (int r = 0; r < 4; ++r) {
      int row = m0 + wr * 64 + i * 16 + quad * 4 + r;
      long base = (long)row * ldc + n0 + wc * 64;
      float rb_ = rowbias ? bias[row] : 0.f;
#pragma unroll
      for (int j = 0; j < 4; ++j) {
        float v = acc[i][j][r] + (rowbias ? rb_ : cb[j]);
        if (STORE_BF16) ((u16*)Cout)[base + j * 16 + l15] = f2bf(v);
        else            ((float*)Cout)[base + j * 16 + l15] = v;
      }
    }
  }
}

// ---------------------------------------------------------------- fused QKV + V^T GEMM
__global__ __launch_bounds__(256) void gemm_qkv(
    const u16* __restrict__ xb, const u16* __restrict__ wqb,
    const u16* __restrict__ wkb, const u16* __restrict__ wvb,
    const float* __restrict__ bq, const float* __restrict__ bk,
    const float* __restrict__ bv,
    u16* __restrict__ Qb, u16* __restrict__ Kb, u16* __restrict__ Vtg) {
  const int bx = blockIdx.x;
  const u16 *AT, *BT;
  const float* bias;
  u16* C;
  int m0, n0, ldc;
  bool rowbias;
  if (bx < 512) {
    int g = bx >> 5;
    int sel = g >> 3;
    n0 = (g & 7) * 128; m0 = (bx & 31) * 128;
    AT = xb; BT = sel ? wkb : wqb; bias = sel ? bk : bq;
    C = sel ? Kb : Qb; ldc = 1024; rowbias = false;
  } else {
    int rem = bx - 512;
    n0 = (rem >> 3) * 128; m0 = (rem & 7) * 128;
    AT = wvb; BT = xb; bias = bv;
    C = Vtg; ldc = 4096; rowbias = true;
  }
  gemm_body<true>(AT, BT, bias, rowbias, C, ldc, m0, n0);
}

// ---------------------------------------------------------------- output GEMM
__global__ __launch_bounds__(256) void gemm_out(
    const u16* __restrict__ A, const u16* __restrict__ B,
    const float* __restrict__ bias, float* __restrict__ C) {
  gemm_body<false>(A, B, bias, false, C, 1024, blockIdx.x * 128, blockIdx.y * 128);
}

// ---------------------------------------------------------------- attention (split-K, S^T)
// As round 6, plus register prefetch of chunk c+1's K/V during chunk-c compute and a
// raw trailing s_barrier (no vmcnt drain on the prefetch).
__global__ __launch_bounds__(256) void attn_split(
    const u16* __restrict__ Qb,     // [4096][1024]
    const u16* __restrict__ Kb,     // [4096][1024]
    const u16* __restrict__ Vtg,    // [1024][4096] V^T
    const float* __restrict__ rel_bias,  // [63][16]
    u16* __restrict__ att,          // == Qb (in-place, disjoint rows)
    u16* __restrict__ Opart,        // [1024][64][64]
    float* __restrict__ Dpart) {    // [1024][64]
  constexpr int WS = 68;
  __shared__ __align__(16) u16 Kt[64 * 64];
  __shared__ __align__(16) u16 Vt[64 * 64];
  __shared__ __align__(16) u16 Ws[4][16 * WS];
  __shared__ float biasl[64];

  const int bx = blockIdx.x;
  const int bh = bx / 24;
  const int slot = bx - bh * 24;
  const int b = bh >> 4, h = bh & 15;

  int qb, cbeg, cend, pidx;
  bool multi;
  if (slot < 8) { qb = slot; cbeg = 0; cend = qb; multi = false; pidx = 0; }
  else {
    int s = slot - 8;
    qb = 8 + (s >> 1);
    int part = s & 1;
    multi = true;
    pidx = (bh * 8 + (qb - 8)) * 2 + part;
    if (part == 0) { cbeg = 0; cend = 7; }
    else           { cbeg = 8; cend = qb; }
  }
  const int q0 = qb * 64;

  const int t = threadIdx.x;
  const int lane = t & 63;
  const int wv = t >> 6;
  const int quad = lane >> 4;
  const int l15 = lane & 15;

  if (t < 63) biasl[t] = rel_bias[t * 16 + h];
  const float b0c = rel_bias[h];           // clipped bias for dd <= -31

  const long qrow = (long)(b * 1024 + q0 + wv * 16 + l15) * 1024 + h * 64;
  bf16x8 qf0 = *(const bf16x8*)&Qb[qrow + quad * 8];
  bf16x8 qf1 = *(const bf16x8*)&Qb[qrow + 32 + quad * 8];

  const f32x4 vzero = {0.f, 0.f, 0.f, 0.f};
  f32x4 acc_o[4];
#pragma unroll
  for (int j = 0; j < 4; ++j) acc_o[j] = vzero;
  float denom = 0.f;
  const float scale = 0.125f;  // 64^-0.5
  const int ql = q0 + wv * 16 + l15;
  const int sw0 = (quad ^ (l15 & 7)) * 8;
  const int sw1 = ((4 + quad) ^ (l15 & 7)) * 8;

  // prologue: load first chunk's K/V into registers
  uint4 kreg[2], vreg[2];
  {
    const int k0 = cbeg * 64;
#pragma unroll
    for (int p = 0; p < 2; ++p) {
      int idx = t + p * 256;
      int row = idx >> 3, seg = idx & 7;
      kreg[p] = *(const uint4*)&Kb[(long)(b * 1024 + k0 + row) * 1024 + h * 64 + seg * 8];
      vreg[p] = *(const uint4*)&Vtg[(long)(h * 64 + row) * 4096 + b * 1024 + k0 + seg * 8];
    }
  }

  for (int c = cbeg; c <= cend; ++c) {
    const int k0 = c * 64;
    // commit current chunk's regs into swizzled LDS
#pragma unroll
    for (int p = 0; p < 2; ++p) {
      int idx = t + p * 256;
      int row = idx >> 3, seg = idx & 7;
      int sw = row * 64 + ((seg ^ (row & 7)) * 8);
      *(uint4*)&Kt[sw] = kreg[p];
      *(uint4*)&Vt[sw] = vreg[p];
    }
    __syncthreads();   // lgkm drain; no vmem outstanding here
    // prefetch next chunk during compute
    if (c < cend) {
      const int k0n = k0 + 64;
#pragma unroll
      for (int p = 0; p < 2; ++p) {
        int idx = t + p * 256;
        int row = idx >> 3, seg = idx & 7;
        kreg[p] = *(const uint4*)&Kb[(long)(b * 1024 + k0n + row) * 1024 + h * 64 + seg * 8];
        vreg[p] = *(const uint4*)&Vtg[(long)(h * 64 + row) * 4096 + b * 1024 + k0n + seg * 8];
      }
    }

    const bool fast = (c <= qb - 2);
#pragma unroll
    for (int g = 0; g < 4; ++g) {
      const u16* kr = &Kt[(g * 16 + l15) * 64];
      bf16x8 kf0 = *(const bf16x8*)&kr[sw0];
      bf16x8 kf1 = *(const bf16x8*)&kr[sw1];
      f32x4 sT = vzero;
      sT = __builtin_amdgcn_mfma_f32_16x16x32_bf16(kf0, qf0, sT, 0, 0, 0);
      sT = __builtin_amdgcn_mfma_f32_16x16x32_bf16(kf1, qf1, sT, 0, 0, 0);
      const int kgb = k0 + g * 16 + quad * 4;
      ushort4 wpk;
      if (fast) {
#pragma unroll
        for (int r = 0; r < 4; ++r) {
          float w = fmaxf(sT[r] * scale + b0c, 0.f) + 1e-6f;
          u16 wb = f2bf(w);
          denom += bf2f(wb);
          ((u16*)&wpk)[r] = wb;
        }
      } else {
#pragma unroll
        for (int r = 0; r < 4; ++r) {
          int kg = kgb + r;
          int dd = kg - ql;
          dd = dd < -31 ? -31 : (dd > 31 ? 31 : dd);
          float sv = sT[r] * scale + biasl[dd + 31];
          float w = (kg <= ql) ? (fmaxf(sv, 0.f) + 1e-6f) : 0.f;
          u16 wb = f2bf(w);
          denom += bf2f(wb);
          ((u16*)&wpk)[r] = wb;
        }
      }
      *(ushort4*)&Ws[wv][l15 * WS + g * 16 + quad * 4] = wpk;
    }
    asm volatile("s_waitcnt lgkmcnt(0)" ::: "memory");   // Ws wave-private W->R
#pragma unroll
    for (int ks = 0; ks < 64; ks += 32) {
      union { bf16x8 v8; bf16x4 v4[2]; } au;
      int wbase = l15 * WS + ks + quad * 8;
      au.v4[0] = *(const bf16x4*)&Ws[wv][wbase];
      au.v4[1] = *(const bf16x4*)&Ws[wv][wbase + 4];
      const int sv = ks ? sw1 : sw0;
#pragma unroll
      for (int j = 0; j < 4; ++j) {
        bf16x8 bvv = *(const bf16x8*)&Vt[(j * 16 + l15) * 64 + sv];
        acc_o[j] = __builtin_amdgcn_mfma_f32_16x16x32_bf16(au.v8, bvv, acc_o[j], 0, 0, 0);
      }
    }
    // raw barrier: LDS reads of chunk c done before next iter's LDS writes;
    // deliberately no vmcnt drain (prefetch stays in flight)
    asm volatile("s_barrier" ::: "memory");
  }

  denom += __shfl_xor(denom, 16);
  denom += __shfl_xor(denom, 32);

  if (!multi) {
    float invm = 1.f / (denom + 1e-6f);
    float inv[4];
#pragma unroll
    for (int r = 0; r < 4; ++r) inv[r] = __shfl(invm, quad * 4 + r);
#pragma unroll
    for (int j = 0; j < 4; ++j)
#pragma unroll
      for (int r = 0; r < 4; ++r) {
        int q = q0 + wv * 16 + quad * 4 + r;
        att[(long)(b * 1024 + q) * 1024 + h * 64 + j * 16 + l15] = f2bf(acc_o[j][r] * inv[r]);
      }
  } else {
    const int qrel = wv * 16 + quad * 4;
#pragma unroll
    for (int j = 0; j < 4; ++j)
#pragma unroll
      for (int r = 0; r < 4; ++r)
        Opart[(long)pidx * 4096 + (qrel + r) * 64 + j * 16 + l15] = f2bf(acc_o[j][r]);
    if (quad == 0) Dpart[pidx * 64 + wv * 16 + l15] = denom;
  }
}

// ---------------------------------------------------------------- partial combine
__global__ __launch_bounds__(256) void attn_reduce(
    const u16* __restrict__ Opart, const float* __restrict__ Dpart,
    u16* __restrict__ att) {
  const int bx = blockIdx.x;
  const int bh = bx >> 3;
  const int q8 = bx & 7;
  const int b = bh >> 4, h = bh & 15;
  const int qb = 8 + q8;
  const int pidx = (bh * 8 + q8) * 2;

  const int t = threadIdx.x;
  const int row = t >> 2;
  const int dseg = t & 3;

  const float d0 = Dpart[pidx * 64 + row];
  const float d1 = Dpart[(pidx + 1) * 64 + row];
  const float inv = 1.f / (d0 + d1 + 1e-6f);

  const u16* O0 = Opart + (long)pidx * 4096 + row * 64 + dseg * 16;
  const u16* O1 = O0 + 4096;
  union { uint4 q[2]; u16 s[16]; } a, c, o;
  a.q[0] = *(const uint4*)O0;       a.q[1] = *(const uint4*)(O0 + 8);
  c.q[0] = *(const uint4*)O1;       c.q[1] = *(const uint4*)(O1 + 8);
#pragma unroll
  for (int i = 0; i < 16; ++i) o.s[i] = f2bf((bf2f(a.s[i]) + bf2f(c.s[i])) * inv);
  u16* dst = att + (long)(b * 1024 + qb * 64 + row) * 1024 + h * 64 + dseg * 16;
  *(uint4*)dst = o.q[0];
  *(uint4*)(dst + 8) = o.q[1];
}

// ---------------------------------------------------------------- launch
extern "C" void kernel_launch(void* const* d_in, const int* in_sizes, int n_in,
                              void* d_out, int out_size, void* d_ws, size_t ws_size,
                              hipStream_t stream) {
  const float* x  = (const float*)d_in[0];
  const float* Wq = (const float*)d_in[2];
  const float* bq = (const float*)d_in[3];
  const float* Wk = (const float*)d_in[4];
  const float* bk = (const float*)d_in[5];
  const float* Wv = (const float*)d_in[6];
  const float* bv = (const float*)d_in[7];
  const float* Wo = (const float*)d_in[8];
  const float* bo = (const float*)d_in[9];
  const float* rb = (const float*)d_in[10];

  char* ws = (char*)d_ws;
  u16* xb      = (u16*)(ws);
  u16* Opart   = (u16*)(ws);                 // reuses xb after QKV
  u16* wqb     = (u16*)(ws + (8l  << 20));
  float* Dpart = (float*)(ws + (8l << 20));  // reuses wqb after QKV
  u16* wkb     = (u16*)(ws + (10l << 20));
  u16* wvb     = (u16*)(ws + (12l << 20));
  u16* wob     = (u16*)(ws + (14l << 20));
  u16* Qb      = (u16*)(ws + (16l << 20));
  u16* Kb      = (u16*)d_out;
  u16* Vtg     = (u16*)((char*)d_out + (8l << 20));

  cast_all_kernel<<<8192, 256, 0, stream>>>(x, Wq, Wk, Wv, Wo, xb, wqb, wkb, wvb, wob);
  gemm_qkv<<<768, 256, 0, stream>>>(xb, wqb, wkb, wvb, bq, bk, bv, Qb, Kb, Vtg);
  attn_split<<<1536, 256, 0, stream>>>(Qb, Kb, Vtg, rb, Qb, Opart, Dpart);
  attn_reduce<<<512, 256, 0, stream>>>(Opart, Dpart, Qb);
  gemm_out<<<dim3(32, 8), 256, 0, stream>>>(Qb, wob, bo, (float*)d_out);
}

// Round 8
// 198.132 us; speedup vs baseline: 1.2329x; 1.2329x over previous
//
#include <hip/hip_runtime.h>

// AlgebraicAttention on MI355X (gfx950), round 8.
// R7 post-mortem: register prefetch in attn spilled to scratch (WRITE_SIZE 8->110MB)
// -> revert attn to R6. Swizzle proven: attn conflicts = 0. R6 gemm carries 9.4M
// conflict-cycles (row-major [row][64] tile: 16-way on every b128 frag read).
// Fix: swizzle the GLOBAL SOURCE of global_load_lds (seg' = seg^(row&7)) so the
// landed LDS layout is conflict-free; frag reads use sw0/sw1 like attention.
// ws: [0,8M) xb->Opart | [8,10M) wqb->Dpart | [10,12M) wkb | [12,14M) wvb |
//     [14,16M) wob | [16,24M) Qb (att in-place). d_out: [0,8M) Kb | [8,16M) Vtg.

typedef __attribute__((ext_vector_type(8))) __bf16 bf16x8;
typedef __attribute__((ext_vector_type(4))) __bf16 bf16x4;
typedef __attribute__((ext_vector_type(4))) float f32x4;
typedef unsigned short u16;

__device__ __forceinline__ u16 f2bf(float f) {
  unsigned u = __float_as_uint(f);
  u += 0x7FFFu + ((u >> 16) & 1u);   // round-to-nearest-even
  return (u16)(u >> 16);
}
__device__ __forceinline__ float bf2f(u16 b) {
  return __uint_as_float(((unsigned)b) << 16);
}
__device__ __forceinline__ void gl_lds16(const void* g, void* l) {
  __builtin_amdgcn_global_load_lds((__attribute__((address_space(1))) void*)g,
                                   (__attribute__((address_space(3))) void*)l,
                                   16, 0, 0);
}

// ---------------------------------------------------------------- cast kernel
__global__ __launch_bounds__(256) void cast_all_kernel(
    const float* __restrict__ x,  const float* __restrict__ wq,
    const float* __restrict__ wk, const float* __restrict__ wv,
    const float* __restrict__ wo,
    u16* __restrict__ xb, u16* __restrict__ wqb, u16* __restrict__ wkb,
    u16* __restrict__ wvb, u16* __restrict__ wob) {
  long i4 = (long)blockIdx.x * 256 + threadIdx.x;
  const float* src; u16* dst; long rel;
  if (i4 < 1048576) { src = x; dst = xb; rel = i4; }
  else {
    long j = i4 - 1048576;
    int w = (int)(j >> 18);
    rel = j & 262143;
    src = (w == 0) ? wq : (w == 1) ? wk : (w == 2) ? wv : wo;
    dst = (w == 0) ? wqb : (w == 1) ? wkb : (w == 2) ? wvb : wob;
  }
  float4 v = ((const float4*)src)[rel];
  ushort4 o;
  o.x = f2bf(v.x); o.y = f2bf(v.y); o.z = f2bf(v.z); o.w = f2bf(v.w);
  ((ushort4*)dst)[rel] = o;
}

// ---------------------------------------------------------------- GEMM body (swizzled)
// C = A @ B^T (+bias). 128x128 tile, BK=64, single-buffer LDS, m97 gl_lds staging.
// LDS layout swizzled at the SOURCE: LDS[row][seg] holds global seg^(row&7); frag
// reads at (quad^(l15&7)) land on 32 distinct banks across each 8-lane group.
template <bool STORE_BF16>
__device__ __forceinline__ void gemm_body(
    const u16* __restrict__ A, const u16* __restrict__ B,
    const float* __restrict__ bias, bool rowbias,
    void* __restrict__ Cout, int ldc, int m0, int n0) {
  constexpr int K = 1024;
  __shared__ __align__(16) u16 As[128 * 64];
  __shared__ __align__(16) u16 Bs[128 * 64];

  const int t = threadIdx.x;
  const int lane = t & 63;
  const int wv = t >> 6;
  const int quad = lane >> 4;
  const int l15 = lane & 15;
  const int wr = wv >> 1, wc = wv & 1;
  const int sw0 = (quad ^ (l15 & 7)) * 8;        // k-seg quad   (ks=0)
  const int sw1 = ((4 + quad) ^ (l15 & 7)) * 8;  // k-seg quad+4 (ks=32)

  const f32x4 vzero = {0.f, 0.f, 0.f, 0.f};
  f32x4 acc[4][4];
#pragma unroll
  for (int i = 0; i < 4; ++i)
#pragma unroll
    for (int j = 0; j < 4; ++j) acc[i][j] = vzero;

  for (int kt = 0; kt < K / 64; ++kt) {
    const int k0 = kt * 64;
#pragma unroll
    for (int p = 0; p < 4; ++p) {
      int idx = t + p * 256;
      int row = idx >> 3, seg = idx & 7;
      int sseg = seg ^ (row & 7);   // source-side swizzle
      gl_lds16(&A[(long)(m0 + row) * K + k0 + sseg * 8], &As[idx * 8]);
      gl_lds16(&B[(long)(n0 + row) * K + k0 + sseg * 8], &Bs[idx * 8]);
    }
    __syncthreads();
#pragma unroll
    for (int ks = 0; ks < 64; ks += 32) {
      const int sw = ks ? sw1 : sw0;
      bf16x8 af[4], bfg[4];
#pragma unroll
      for (int i = 0; i < 4; ++i)
        af[i] = *(const bf16x8*)&As[(wr * 64 + i * 16 + l15) * 64 + sw];
#pragma unroll
      for (int j = 0; j < 4; ++j)
        bfg[j] = *(const bf16x8*)&Bs[(wc * 64 + j * 16 + l15) * 64 + sw];
#pragma unroll
      for (int i = 0; i < 4; ++i)
#pragma unroll
        for (int j = 0; j < 4; ++j)
          acc[i][j] = __builtin_amdgcn_mfma_f32_16x16x32_bf16(af[i], bfg[j], acc[i][j], 0, 0, 0);
    }
    __syncthreads();
  }

  float cb[4];
  if (!rowbias) {
#pragma unroll
    for (int j = 0; j < 4; ++j) cb[j] = bias[n0 + wc * 64 + j * 16 + l15];
  }

#pragma unroll
  for (int i = 0; i < 4; ++i) {
#pragma unroll
    for (int r = 0; r < 4; ++r) {
      int row = m0 + wr * 64 + i * 16 + quad * 4 + r;
      long base = (long)row * ldc + n0 + wc * 64;
      float rb_ = rowbias ? bias[row] : 0.f;
#pragma unroll
      for (int j = 0; j < 4; ++j) {
        float v = acc[i][j][r] + (rowbias ? rb_ : cb[j]);
        if (STORE_BF16) ((u16*)Cout)[base + j * 16 + l15] = f2bf(v);
        else            ((float*)Cout)[base + j * 16 + l15] = v;
      }
    }
  }
}

// ---------------------------------------------------------------- fused QKV + V^T GEMM
__global__ __launch_bounds__(256) void gemm_qkv(
    const u16* __restrict__ xb, const u16* __restrict__ wqb,
    const u16* __restrict__ wkb, const u16* __restrict__ wvb,
    const float* __restrict__ bq, const float* __restrict__ bk,
    const float* __restrict__ bv,
    u16* __restrict__ Qb, u16* __restrict__ Kb, u16* __restrict__ Vtg) {
  const int bx = blockIdx.x;
  const u16 *AT, *BT;
  const float* bias;
  u16* C;
  int m0, n0, ldc;
  bool rowbias;
  if (bx < 512) {
    int g = bx >> 5;
    int sel = g >> 3;
    n0 = (g & 7) * 128; m0 = (bx & 31) * 128;
    AT = xb; BT = sel ? wkb : wqb; bias = sel ? bk : bq;
    C = sel ? Kb : Qb; ldc = 1024; rowbias = false;
  } else {
    int rem = bx - 512;
    n0 = (rem >> 3) * 128; m0 = (rem & 7) * 128;
    AT = wvb; BT = xb; bias = bv;
    C = Vtg; ldc = 4096; rowbias = true;
  }
  gemm_body<true>(AT, BT, bias, rowbias, C, ldc, m0, n0);
}

// ---------------------------------------------------------------- output GEMM
__global__ __launch_bounds__(256) void gemm_out(
    const u16* __restrict__ A, const u16* __restrict__ B,
    const float* __restrict__ bias, float* __restrict__ C) {
  gemm_body<false>(A, B, bias, false, C, 1024, blockIdx.x * 128, blockIdx.y * 128);
}

// ---------------------------------------------------------------- attention (split-K, S^T)
// Exactly round 6 (known-good): register->swizzled-LDS staging, S^T MFMA, b64 Ws
// spill, constant-bias fast path, split-K partials. No cross-iter prefetch (r7 spilled).
__global__ __launch_bounds__(256) void attn_split(
    const u16* __restrict__ Qb,     // [4096][1024]
    const u16* __restrict__ Kb,     // [4096][1024]
    const u16* __restrict__ Vtg,    // [1024][4096] V^T
    const float* __restrict__ rel_bias,  // [63][16]
    u16* __restrict__ att,          // == Qb (in-place, disjoint rows)
    u16* __restrict__ Opart,        // [1024][64][64]
    float* __restrict__ Dpart) {    // [1024][64]
  constexpr int WS = 68;
  __shared__ __align__(16) u16 Kt[64 * 64];
  __shared__ __align__(16) u16 Vt[64 * 64];
  __shared__ __align__(16) u16 Ws[4][16 * WS];
  __shared__ float biasl[64];

  const int bx = blockIdx.x;
  const int bh = bx / 24;
  const int slot = bx - bh * 24;
  const int b = bh >> 4, h = bh & 15;

  int qb, cbeg, cend, pidx;
  bool multi;
  if (slot < 8) { qb = slot; cbeg = 0; cend = qb; multi = false; pidx = 0; }
  else {
    int s = slot - 8;
    qb = 8 + (s >> 1);
    int part = s & 1;
    multi = true;
    pidx = (bh * 8 + (qb - 8)) * 2 + part;
    if (part == 0) { cbeg = 0; cend = 7; }
    else           { cbeg = 8; cend = qb; }
  }
  const int q0 = qb * 64;

  const int t = threadIdx.x;
  const int lane = t & 63;
  const int wv = t >> 6;
  const int quad = lane >> 4;
  const int l15 = lane & 15;

  if (t < 63) biasl[t] = rel_bias[t * 16 + h];
  const float b0c = rel_bias[h];           // clipped bias for dd <= -31

  const long qrow = (long)(b * 1024 + q0 + wv * 16 + l15) * 1024 + h * 64;
  bf16x8 qf0 = *(const bf16x8*)&Qb[qrow + quad * 8];
  bf16x8 qf1 = *(const bf16x8*)&Qb[qrow + 32 + quad * 8];

  const f32x4 vzero = {0.f, 0.f, 0.f, 0.f};
  f32x4 acc_o[4];
#pragma unroll
  for (int j = 0; j < 4; ++j) acc_o[j] = vzero;
  float denom = 0.f;
  const float scale = 0.125f;  // 64^-0.5
  const int ql = q0 + wv * 16 + l15;
  const int sw0 = (quad ^ (l15 & 7)) * 8;
  const int sw1 = ((4 + quad) ^ (l15 & 7)) * 8;

  for (int c = cbeg; c <= cend; ++c) {
    const int k0 = c * 64;
    if (c != cbeg) __syncthreads();
#pragma unroll
    for (int p = 0; p < 2; ++p) {
      int idx = t + p * 256;
      int row = idx >> 3, seg = idx & 7;
      int sw = row * 64 + ((seg ^ (row & 7)) * 8);
      uint4 kv = *(const uint4*)&Kb[(long)(b * 1024 + k0 + row) * 1024 + h * 64 + seg * 8];
      uint4 vv = *(const uint4*)&Vtg[(long)(h * 64 + row) * 4096 + b * 1024 + k0 + seg * 8];
      *(uint4*)&Kt[sw] = kv;
      *(uint4*)&Vt[sw] = vv;
    }
    __syncthreads();

    const bool fast = (c <= qb - 2);
#pragma unroll
    for (int g = 0; g < 4; ++g) {
      const u16* kr = &Kt[(g * 16 + l15) * 64];
      bf16x8 kf0 = *(const bf16x8*)&kr[sw0];
      bf16x8 kf1 = *(const bf16x8*)&kr[sw1];
      f32x4 sT = vzero;
      sT = __builtin_amdgcn_mfma_f32_16x16x32_bf16(kf0, qf0, sT, 0, 0, 0);
      sT = __builtin_amdgcn_mfma_f32_16x16x32_bf16(kf1, qf1, sT, 0, 0, 0);
      const int kgb = k0 + g * 16 + quad * 4;
      ushort4 wpk;
      if (fast) {
#pragma unroll
        for (int r = 0; r < 4; ++r) {
          float w = fmaxf(sT[r] * scale + b0c, 0.f) + 1e-6f;
          u16 wb = f2bf(w);
          denom += bf2f(wb);
          ((u16*)&wpk)[r] = wb;
        }
      } else {
#pragma unroll
        for (int r = 0; r < 4; ++r) {
          int kg = kgb + r;
          int dd = kg - ql;
          dd = dd < -31 ? -31 : (dd > 31 ? 31 : dd);
          float sv = sT[r] * scale + biasl[dd + 31];
          float w = (kg <= ql) ? (fmaxf(sv, 0.f) + 1e-6f) : 0.f;
          u16 wb = f2bf(w);
          denom += bf2f(wb);
          ((u16*)&wpk)[r] = wb;
        }
      }
      *(ushort4*)&Ws[wv][l15 * WS + g * 16 + quad * 4] = wpk;
    }
    asm volatile("s_waitcnt lgkmcnt(0)" ::: "memory");   // Ws wave-private W->R
#pragma unroll
    for (int ks = 0; ks < 64; ks += 32) {
      union { bf16x8 v8; bf16x4 v4[2]; } au;
      int wbase = l15 * WS + ks + quad * 8;
      au.v4[0] = *(const bf16x4*)&Ws[wv][wbase];
      au.v4[1] = *(const bf16x4*)&Ws[wv][wbase + 4];
      const int sv = ks ? sw1 : sw0;
#pragma unroll
      for (int j = 0; j < 4; ++j) {
        bf16x8 bvv = *(const bf16x8*)&Vt[(j * 16 + l15) * 64 + sv];
        acc_o[j] = __builtin_amdgcn_mfma_f32_16x16x32_bf16(au.v8, bvv, acc_o[j], 0, 0, 0);
      }
    }
  }

  denom += __shfl_xor(denom, 16);
  denom += __shfl_xor(denom, 32);

  if (!multi) {
    float invm = 1.f / (denom + 1e-6f);
    float inv[4];
#pragma unroll
    for (int r = 0; r < 4; ++r) inv[r] = __shfl(invm, quad * 4 + r);
#pragma unroll
    for (int j = 0; j < 4; ++j)
#pragma unroll
      for (int r = 0; r < 4; ++r) {
        int q = q0 + wv * 16 + quad * 4 + r;
        att[(long)(b * 1024 + q) * 1024 + h * 64 + j * 16 + l15] = f2bf(acc_o[j][r] * inv[r]);
      }
  } else {
    const int qrel = wv * 16 + quad * 4;
#pragma unroll
    for (int j = 0; j < 4; ++j)
#pragma unroll
      for (int r = 0; r < 4; ++r)
        Opart[(long)pidx * 4096 + (qrel + r) * 64 + j * 16 + l15] = f2bf(acc_o[j][r]);
    if (quad == 0) Dpart[pidx * 64 + wv * 16 + l15] = denom;
  }
}

// ---------------------------------------------------------------- partial combine
__global__ __launch_bounds__(256) void attn_reduce(
    const u16* __restrict__ Opart, const float* __restrict__ Dpart,
    u16* __restrict__ att) {
  const int bx = blockIdx.x;
  const int bh = bx >> 3;
  const int q8 = bx & 7;
  const int b = bh >> 4, h = bh & 15;
  const int qb = 8 + q8;
  const int pidx = (bh * 8 + q8) * 2;

  const int t = threadIdx.x;
  const int row = t >> 2;
  const int dseg = t & 3;

  const float d0 = Dpart[pidx * 64 + row];
  const float d1 = Dpart[(pidx + 1) * 64 + row];
  const float inv = 1.f / (d0 + d1 + 1e-6f);

  const u16* O0 = Opart + (long)pidx * 4096 + row * 64 + dseg * 16;
  const u16* O1 = O0 + 4096;
  union { uint4 q[2]; u16 s[16]; } a, c, o;
  a.q[0] = *(const uint4*)O0;       a.q[1] = *(const uint4*)(O0 + 8);
  c.q[0] = *(const uint4*)O1;       c.q[1] = *(const uint4*)(O1 + 8);
#pragma unroll
  for (int i = 0; i < 16; ++i) o.s[i] = f2bf((bf2f(a.s[i]) + bf2f(c.s[i])) * inv);
  u16* dst = att + (long)(b * 1024 + qb * 64 + row) * 1024 + h * 64 + dseg * 16;
  *(uint4*)dst = o.q[0];
  *(uint4*)(dst + 8) = o.q[1];
}

// ---------------------------------------------------------------- launch
extern "C" void kernel_launch(void* const* d_in, const int* in_sizes, int n_in,
                              void* d_out, int out_size, void* d_ws, size_t ws_size,
                              hipStream_t stream) {
  const float* x  = (const float*)d_in[0];
  const float* Wq = (const float*)d_in[2];
  const float* bq = (const float*)d_in[3];
  const float* Wk = (const float*)d_in[4];
  const float* bk = (const float*)d_in[5];
  const float* Wv = (const float*)d_in[6];
  const float* bv = (const float*)d_in[7];
  const float* Wo = (const float*)d_in[8];
  const float* bo = (const float*)d_in[9];
  const float* rb = (const float*)d_in[10];

  char* ws = (char*)d_ws;
  u16* xb      = (u16*)(ws);
  u16* Opart   = (u16*)(ws);                 // reuses xb after QKV
  u16* wqb     = (u16*)(ws + (8l  << 20));
  float* Dpart = (float*)(ws + (8l << 20));  // reuses wqb after QKV
  u16* wkb     = (u16*)(ws + (10l << 20));
  u16* wvb     = (u16*)(ws + (12l << 20));
  u16* wob     = (u16*)(ws + (14l << 20));
  u16* Qb      = (u16*)(ws + (16l << 20));
  u16* Kb      = (u16*)d_out;
  u16* Vtg     = (u16*)((char*)d_out + (8l << 20));

  cast_all_kernel<<<8192, 256, 0, stream>>>(x, Wq, Wk, Wv, Wo, xb, wqb, wkb, wvb, wob);
  gemm_qkv<<<768, 256, 0, stream>>>(xb, wqb, wkb, wvb, bq, bk, bv, Qb, Kb, Vtg);
  attn_split<<<1536, 256, 0, stream>>>(Qb, Kb, Vtg, rb, Qb, Opart, Dpart);
  attn_reduce<<<512, 256, 0, stream>>>(Opart, Dpart, Qb);
  gemm_out<<<dim3(32, 8), 256, 0, stream>>>(Qb, wob, bo, (float*)d_out);
}

// Round 9
// 195.456 us; speedup vs baseline: 1.2498x; 1.0137x over previous
//
#include <hip/hip_runtime.h>

// AlgebraicAttention on MI355X (gfx950), round 9.
// R8 post-mortem: gemm conflicts 0 but still 60us = 10.7 B/cyc/CU staging (m97 sustains
// 21.8 on same structure) -> 16-iter K-loop never amortizes the vmcnt(0)+barrier drain.
// Fix (clean retest of r7's gemm, which passed correctness but was confounded by the
// attn spill): double-buffered LDS K-loop, raw s_barrier + s_waitcnt vmcnt(8) so tile
// kt+1's loads stay in flight across the barrier. Attention byte-identical to r8.
// ws: [0,8M) xb->Opart | [8,10M) wqb->Dpart | [10,12M) wkb | [12,14M) wvb |
//     [14,16M) wob | [16,24M) Qb (att in-place). d_out: [0,8M) Kb | [8,16M) Vtg.

typedef __attribute__((ext_vector_type(8))) __bf16 bf16x8;
typedef __attribute__((ext_vector_type(4))) __bf16 bf16x4;
typedef __attribute__((ext_vector_type(4))) float f32x4;
typedef unsigned short u16;

__device__ __forceinline__ u16 f2bf(float f) {
  unsigned u = __float_as_uint(f);
  u += 0x7FFFu + ((u >> 16) & 1u);   // round-to-nearest-even
  return (u16)(u >> 16);
}
__device__ __forceinline__ float bf2f(u16 b) {
  return __uint_as_float(((unsigned)b) << 16);
}
__device__ __forceinline__ void gl_lds16(const void* g, void* l) {
  __builtin_amdgcn_global_load_lds((__attribute__((address_space(1))) void*)g,
                                   (__attribute__((address_space(3))) void*)l,
                                   16, 0, 0);
}

// ---------------------------------------------------------------- cast kernel
__global__ __launch_bounds__(256) void cast_all_kernel(
    const float* __restrict__ x,  const float* __restrict__ wq,
    const float* __restrict__ wk, const float* __restrict__ wv,
    const float* __restrict__ wo,
    u16* __restrict__ xb, u16* __restrict__ wqb, u16* __restrict__ wkb,
    u16* __restrict__ wvb, u16* __restrict__ wob) {
  long i4 = (long)blockIdx.x * 256 + threadIdx.x;
  const float* src; u16* dst; long rel;
  if (i4 < 1048576) { src = x; dst = xb; rel = i4; }
  else {
    long j = i4 - 1048576;
    int w = (int)(j >> 18);
    rel = j & 262143;
    src = (w == 0) ? wq : (w == 1) ? wk : (w == 2) ? wv : wo;
    dst = (w == 0) ? wqb : (w == 1) ? wkb : (w == 2) ? wvb : wob;
  }
  float4 v = ((const float4*)src)[rel];
  ushort4 o;
  o.x = f2bf(v.x); o.y = f2bf(v.y); o.z = f2bf(v.z); o.w = f2bf(v.w);
  ((ushort4*)dst)[rel] = o;
}

// ---------------------------------------------------------------- GEMM body
// C = A @ B^T (+bias). 128x128 tile, BK=64, DOUBLE-buffered swizzled LDS.
// Pipeline: stage(kt+1) -> vmcnt(8) (= tile kt resident, kt+1 in flight) ->
// s_barrier -> compute(kt) -> s_barrier. Source-side swizzle keeps frag reads
// conflict-free (r8: SQ_LDS_BANK_CONFLICT == 0).
template <bool STORE_BF16>
__device__ __forceinline__ void gemm_body(
    const u16* __restrict__ A, const u16* __restrict__ B,
    const float* __restrict__ bias, bool rowbias,
    void* __restrict__ Cout, int ldc, int m0, int n0) {
  constexpr int K = 1024;
  constexpr int NT = K / 64;
  __shared__ __align__(16) u16 As[2][128 * 64];
  __shared__ __align__(16) u16 Bs[2][128 * 64];

  const int t = threadIdx.x;
  const int lane = t & 63;
  const int wv = t >> 6;
  const int quad = lane >> 4;
  const int l15 = lane & 15;
  const int wr = wv >> 1, wc = wv & 1;
  const int sw0 = (quad ^ (l15 & 7)) * 8;        // k-seg quad   (ks=0)
  const int sw1 = ((4 + quad) ^ (l15 & 7)) * 8;  // k-seg quad+4 (ks=32)

  const f32x4 vzero = {0.f, 0.f, 0.f, 0.f};
  f32x4 acc[4][4];
#pragma unroll
  for (int i = 0; i < 4; ++i)
#pragma unroll
    for (int j = 0; j < 4; ++j) acc[i][j] = vzero;

  auto stage = [&](int kt, int bufi) {
#pragma unroll
    for (int p = 0; p < 4; ++p) {
      int idx = t + p * 256;
      int row = idx >> 3, seg = idx & 7;
      int sseg = seg ^ (row & 7);   // source-side swizzle
      gl_lds16(&A[(long)(m0 + row) * K + kt * 64 + sseg * 8], &As[bufi][idx * 8]);
      gl_lds16(&B[(long)(n0 + row) * K + kt * 64 + sseg * 8], &Bs[bufi][idx * 8]);
    }
  };

  stage(0, 0);
  for (int kt = 0; kt < NT; ++kt) {
    const int bufi = kt & 1;
    if (kt + 1 < NT) {
      stage(kt + 1, bufi ^ 1);
      asm volatile("s_waitcnt vmcnt(8)" ::: "memory");   // tile kt resident
    } else {
      asm volatile("s_waitcnt vmcnt(0)" ::: "memory");
    }
    asm volatile("s_barrier" ::: "memory");              // all waves: tile kt ready
#pragma unroll
    for (int ks = 0; ks < 64; ks += 32) {
      const int sw = ks ? sw1 : sw0;
      bf16x8 af[4], bfg[4];
#pragma unroll
      for (int i = 0; i < 4; ++i)
        af[i] = *(const bf16x8*)&As[bufi][(wr * 64 + i * 16 + l15) * 64 + sw];
#pragma unroll
      for (int j = 0; j < 4; ++j)
        bfg[j] = *(const bf16x8*)&Bs[bufi][(wc * 64 + j * 16 + l15) * 64 + sw];
#pragma unroll
      for (int i = 0; i < 4; ++i)
#pragma unroll
        for (int j = 0; j < 4; ++j)
          acc[i][j] = __builtin_amdgcn_mfma_f32_16x16x32_bf16(af[i], bfg[j], acc[i][j], 0, 0, 0);
    }
    asm volatile("s_barrier" ::: "memory");  // reads(kt) done before writes(kt+2)
  }

  float cb[4];
  if (!rowbias) {
#pragma unroll
    for (int j = 0; j < 4; ++j) cb[j] = bias[n0 + wc * 64 + j * 16 + l15];
  }

#pragma unroll
  for (int i = 0; i < 4; ++i) {
#pragma unroll
    for (int r = 0; r < 4; ++r) {
      int row = m0 + wr * 64 + i * 16 + quad * 4 + r;
      long base = (long)row * ldc + n0 + wc * 64;
      float rb_ = rowbias ? bias[row] : 0.f;
#pragma unroll
      for (int j = 0; j < 4; ++j) {
        float v = acc[i][j][r] + (rowbias ? rb_ : cb[j]);
        if (STORE_BF16) ((u16*)Cout)[base + j * 16 + l15] = f2bf(v);
        else            ((float*)Cout)[base + j * 16 + l15] = v;
      }
    }
  }
}

// ---------------------------------------------------------------- fused QKV + V^T GEMM
__global__ __launch_bounds__(256) void gemm_qkv(
    const u16* __restrict__ xb, const u16* __restrict__ wqb,
    const u16* __restrict__ wkb, const u16* __restrict__ wvb,
    const float* __restrict__ bq, const float* __restrict__ bk,
    const float* __restrict__ bv,
    u16* __restrict__ Qb, u16* __restrict__ Kb, u16* __restrict__ Vtg) {
  const int bx = blockIdx.x;
  const u16 *AT, *BT;
  const float* bias;
  u16* C;
  int m0, n0, ldc;
  bool rowbias;
  if (bx < 512) {
    int g = bx >> 5;
    int sel = g >> 3;
    n0 = (g & 7) * 128; m0 = (bx & 31) * 128;
    AT = xb; BT = sel ? wkb : wqb; bias = sel ? bk : bq;
    C = sel ? Kb : Qb; ldc = 1024; rowbias = false;
  } else {
    int rem = bx - 512;
    n0 = (rem >> 3) * 128; m0 = (rem & 7) * 128;
    AT = wvb; BT = xb; bias = bv;
    C = Vtg; ldc = 4096; rowbias = true;
  }
  gemm_body<true>(AT, BT, bias, rowbias, C, ldc, m0, n0);
}

// ---------------------------------------------------------------- output GEMM
__global__ __launch_bounds__(256) void gemm_out(
    const u16* __restrict__ A, const u16* __restrict__ B,
    const float* __restrict__ bias, float* __restrict__ C) {
  gemm_body<false>(A, B, bias, false, C, 1024, blockIdx.x * 128, blockIdx.y * 128);
}

// ---------------------------------------------------------------- attention (split-K, S^T)
// Byte-identical to round 8 (known-good, conflicts = 0).
__global__ __launch_bounds__(256) void attn_split(
    const u16* __restrict__ Qb,     // [4096][1024]
    const u16* __restrict__ Kb,     // [4096][1024]
    const u16* __restrict__ Vtg,    // [1024][4096] V^T
    const float* __restrict__ rel_bias,  // [63][16]
    u16* __restrict__ att,          // == Qb (in-place, disjoint rows)
    u16* __restrict__ Opart,        // [1024][64][64]
    float* __restrict__ Dpart) {    // [1024][64]
  constexpr int WS = 68;
  __shared__ __align__(16) u16 Kt[64 * 64];
  __shared__ __align__(16) u16 Vt[64 * 64];
  __shared__ __align__(16) u16 Ws[4][16 * WS];
  __shared__ float biasl[64];

  const int bx = blockIdx.x;
  const int bh = bx / 24;
  const int slot = bx - bh * 24;
  const int b = bh >> 4, h = bh & 15;

  int qb, cbeg, cend, pidx;
  bool multi;
  if (slot < 8) { qb = slot; cbeg = 0; cend = qb; multi = false; pidx = 0; }
  else {
    int s = slot - 8;
    qb = 8 + (s >> 1);
    int part = s & 1;
    multi = true;
    pidx = (bh * 8 + (qb - 8)) * 2 + part;
    if (part == 0) { cbeg = 0; cend = 7; }
    else           { cbeg = 8; cend = qb; }
  }
  const int q0 = qb * 64;

  const int t = threadIdx.x;
  const int lane = t & 63;
  const int wv = t >> 6;
  const int quad = lane >> 4;
  const int l15 = lane & 15;

  if (t < 63) biasl[t] = rel_bias[t * 16 + h];
  const float b0c = rel_bias[h];           // clipped bias for dd <= -31

  const long qrow = (long)(b * 1024 + q0 + wv * 16 + l15) * 1024 + h * 64;
  bf16x8 qf0 = *(const bf16x8*)&Qb[qrow + quad * 8];
  bf16x8 qf1 = *(const bf16x8*)&Qb[qrow + 32 + quad * 8];

  const f32x4 vzero = {0.f, 0.f, 0.f, 0.f};
  f32x4 acc_o[4];
#pragma unroll
  for (int j = 0; j < 4; ++j) acc_o[j] = vzero;
  float denom = 0.f;
  const float scale = 0.125f;  // 64^-0.5
  const int ql = q0 + wv * 16 + l15;
  const int sw0 = (quad ^ (l15 & 7)) * 8;
  const int sw1 = ((4 + quad) ^ (l15 & 7)) * 8;

  for (int c = cbeg; c <= cend; ++c) {
    const int k0 = c * 64;
    if (c != cbeg) __syncthreads();
#pragma unroll
    for (int p = 0; p < 2; ++p) {
      int idx = t + p * 256;
      int row = idx >> 3, seg = idx & 7;
      int sw = row * 64 + ((seg ^ (row & 7)) * 8);
      uint4 kv = *(const uint4*)&Kb[(long)(b * 1024 + k0 + row) * 1024 + h * 64 + seg * 8];
      uint4 vv = *(const uint4*)&Vtg[(long)(h * 64 + row) * 4096 + b * 1024 + k0 + seg * 8];
      *(uint4*)&Kt[sw] = kv;
      *(uint4*)&Vt[sw] = vv;
    }
    __syncthreads();

    const bool fast = (c <= qb - 2);
#pragma unroll
    for (int g = 0; g < 4; ++g) {
      const u16* kr = &Kt[(g * 16 + l15) * 64];
      bf16x8 kf0 = *(const bf16x8*)&kr[sw0];
      bf16x8 kf1 = *(const bf16x8*)&kr[sw1];
      f32x4 sT = vzero;
      sT = __builtin_amdgcn_mfma_f32_16x16x32_bf16(kf0, qf0, sT, 0, 0, 0);
      sT = __builtin_amdgcn_mfma_f32_16x16x32_bf16(kf1, qf1, sT, 0, 0, 0);
      const int kgb = k0 + g * 16 + quad * 4;
      ushort4 wpk;
      if (fast) {
#pragma unroll
        for (int r = 0; r < 4; ++r) {
          float w = fmaxf(sT[r] * scale + b0c, 0.f) + 1e-6f;
          u16 wb = f2bf(w);
          denom += bf2f(wb);
          ((u16*)&wpk)[r] = wb;
        }
      } else {
#pragma unroll
        for (int r = 0; r < 4; ++r) {
          int kg = kgb + r;
          int dd = kg - ql;
          dd = dd < -31 ? -31 : (dd > 31 ? 31 : dd);
          float sv = sT[r] * scale + biasl[dd + 31];
          float w = (kg <= ql) ? (fmaxf(sv, 0.f) + 1e-6f) : 0.f;
          u16 wb = f2bf(w);
          denom += bf2f(wb);
          ((u16*)&wpk)[r] = wb;
        }
      }
      *(ushort4*)&Ws[wv][l15 * WS + g * 16 + quad * 4] = wpk;
    }
    asm volatile("s_waitcnt lgkmcnt(0)" ::: "memory");   // Ws wave-private W->R
#pragma unroll
    for (int ks = 0; ks < 64; ks += 32) {
      union { bf16x8 v8; bf16x4 v4[2]; } au;
      int wbase = l15 * WS + ks + quad * 8;
      au.v4[0] = *(const bf16x4*)&Ws[wv][wbase];
      au.v4[1] = *(const bf16x4*)&Ws[wv][wbase + 4];
      const int sv = ks ? sw1 : sw0;
#pragma unroll
      for (int j = 0; j < 4; ++j) {
        bf16x8 bvv = *(const bf16x8*)&Vt[(j * 16 + l15) * 64 + sv];
        acc_o[j] = __builtin_amdgcn_mfma_f32_16x16x32_bf16(au.v8, bvv, acc_o[j], 0, 0, 0);
      }
    }
  }

  denom += __shfl_xor(denom, 16);
  denom += __shfl_xor(denom, 32);

  if (!multi) {
    float invm = 1.f / (denom + 1e-6f);
    float inv[4];
#pragma unroll
    for (int r = 0; r < 4; ++r) inv[r] = __shfl(invm, quad * 4 + r);
#pragma unroll
    for (int j = 0; j < 4; ++j)
#pragma unroll
      for (int r = 0; r < 4; ++r) {
        int q = q0 + wv * 16 + quad * 4 + r;
        att[(long)(b * 1024 + q) * 1024 + h * 64 + j * 16 + l15] = f2bf(acc_o[j][r] * inv[r]);
      }
  } else {
    const int qrel = wv * 16 + quad * 4;
#pragma unroll
    for (int j = 0; j < 4; ++j)
#pragma unroll
      for (int r = 0; r < 4; ++r)
        Opart[(long)pidx * 4096 + (qrel + r) * 64 + j * 16 + l15] = f2bf(acc_o[j][r]);
    if (quad == 0) Dpart[pidx * 64 + wv * 16 + l15] = denom;
  }
}

// ---------------------------------------------------------------- partial combine
__global__ __launch_bounds__(256) void attn_reduce(
    const u16* __restrict__ Opart, const float* __restrict__ Dpart,
    u16* __restrict__ att) {
  const int bx = blockIdx.x;
  const int bh = bx >> 3;
  const int q8 = bx & 7;
  const int b = bh >> 4, h = bh & 15;
  const int qb = 8 + q8;
  const int pidx = (bh * 8 + q8) * 2;

  const int t = threadIdx.x;
  const int row = t >> 2;
  const int dseg = t & 3;

  const float d0 = Dpart[pidx * 64 + row];
  const float d1 = Dpart[(pidx + 1) * 64 + row];
  const float inv = 1.f / (d0 + d1 + 1e-6f);

  const u16* O0 = Opart + (long)pidx * 4096 + row * 64 + dseg * 16;
  const u16* O1 = O0 + 4096;
  union { uint4 q[2]; u16 s[16]; } a, c, o;
  a.q[0] = *(const uint4*)O0;       a.q[1] = *(const uint4*)(O0 + 8);
  c.q[0] = *(const uint4*)O1;       c.q[1] = *(const uint4*)(O1 + 8);
#pragma unroll
  for (int i = 0; i < 16; ++i) o.s[i] = f2bf((bf2f(a.s[i]) + bf2f(c.s[i])) * inv);
  u16* dst = att + (long)(b * 1024 + qb * 64 + row) * 1024 + h * 64 + dseg * 16;
  *(uint4*)dst = o.q[0];
  *(uint4*)(dst + 8) = o.q[1];
}

// ---------------------------------------------------------------- launch
extern "C" void kernel_launch(void* const* d_in, const int* in_sizes, int n_in,
                              void* d_out, int out_size, void* d_ws, size_t ws_size,
                              hipStream_t stream) {
  const float* x  = (const float*)d_in[0];
  const float* Wq = (const float*)d_in[2];
  const float* bq = (const float*)d_in[3];
  const float* Wk = (const float*)d_in[4];
  const float* bk = (const float*)d_in[5];
  const float* Wv = (const float*)d_in[6];
  const float* bv = (const float*)d_in[7];
  const float* Wo = (const float*)d_in[8];
  const float* bo = (const float*)d_in[9];
  const float* rb = (const float*)d_in[10];

  char* ws = (char*)d_ws;
  u16* xb      = (u16*)(ws);
  u16* Opart   = (u16*)(ws);                 // reuses xb after QKV
  u16* wqb     = (u16*)(ws + (8l  << 20));
  float* Dpart = (float*)(ws + (8l << 20));  // reuses wqb after QKV
  u16* wkb     = (u16*)(ws + (10l << 20));
  u16* wvb     = (u16*)(ws + (12l << 20));
  u16* wob     = (u16*)(ws + (14l << 20));
  u16* Qb      = (u16*)(ws + (16l << 20));
  u16* Kb      = (u16*)d_out;
  u16* Vtg     = (u16*)((char*)d_out + (8l << 20));

  cast_all_kernel<<<8192, 256, 0, stream>>>(x, Wq, Wk, Wv, Wo, xb, wqb, wkb, wvb, wob);
  gemm_qkv<<<768, 256, 0, stream>>>(xb, wqb, wkb, wvb, bq, bk, bv, Qb, Kb, Vtg);
  attn_split<<<1536, 256, 0, stream>>>(Qb, Kb, Vtg, rb, Qb, Opart, Dpart);
  attn_reduce<<<512, 256, 0, stream>>>(Opart, Dpart, Qb);
  gemm_out<<<dim3(32, 8), 256, 0, stream>>>(Qb, wob, bo, (float*)d_out);
}

// Round 10
// 189.324 us; speedup vs baseline: 1.2903x; 1.0324x over previous
//
#include <hip/hip_runtime.h>

// AlgebraicAttention on MI355X (gfx950), round 10.
// R9 post-mortem: gemm_qkv 48.6us (dbuf works); attention still does 136 chunk-stage
// instances/bh (split-K duplicates part0) and attn_reduce costs a dispatch (~14us with
// launch gap). Fix: 128-row q-strips, 512 threads (8 waves), NO split-K: 72 chunk
// instances/bh (-47% staging), same MFMA, no partials, reduce kernel deleted. LPT
// block order (longest strips first). gemm/cast kernels byte-identical to r9.
// ws: [0,8M) xb | [8,10M) wqb | [10,12M) wkb | [12,14M) wvb | [14,16M) wob |
//     [16,24M) Qb (att in-place). d_out: [0,8M) Kb | [8,16M) Vtg (V^T).

typedef __attribute__((ext_vector_type(8))) __bf16 bf16x8;
typedef __attribute__((ext_vector_type(4))) __bf16 bf16x4;
typedef __attribute__((ext_vector_type(4))) float f32x4;
typedef unsigned short u16;

__device__ __forceinline__ u16 f2bf(float f) {
  unsigned u = __float_as_uint(f);
  u += 0x7FFFu + ((u >> 16) & 1u);   // round-to-nearest-even
  return (u16)(u >> 16);
}
__device__ __forceinline__ float bf2f(u16 b) {
  return __uint_as_float(((unsigned)b) << 16);
}
__device__ __forceinline__ void gl_lds16(const void* g, void* l) {
  __builtin_amdgcn_global_load_lds((__attribute__((address_space(1))) void*)g,
                                   (__attribute__((address_space(3))) void*)l,
                                   16, 0, 0);
}

// ---------------------------------------------------------------- cast kernel
__global__ __launch_bounds__(256) void cast_all_kernel(
    const float* __restrict__ x,  const float* __restrict__ wq,
    const float* __restrict__ wk, const float* __restrict__ wv,
    const float* __restrict__ wo,
    u16* __restrict__ xb, u16* __restrict__ wqb, u16* __restrict__ wkb,
    u16* __restrict__ wvb, u16* __restrict__ wob) {
  long i4 = (long)blockIdx.x * 256 + threadIdx.x;
  const float* src; u16* dst; long rel;
  if (i4 < 1048576) { src = x; dst = xb; rel = i4; }
  else {
    long j = i4 - 1048576;
    int w = (int)(j >> 18);
    rel = j & 262143;
    src = (w == 0) ? wq : (w == 1) ? wk : (w == 2) ? wv : wo;
    dst = (w == 0) ? wqb : (w == 1) ? wkb : (w == 2) ? wvb : wob;
  }
  float4 v = ((const float4*)src)[rel];
  ushort4 o;
  o.x = f2bf(v.x); o.y = f2bf(v.y); o.z = f2bf(v.z); o.w = f2bf(v.w);
  ((ushort4*)dst)[rel] = o;
}

// ---------------------------------------------------------------- GEMM body (r9, proven)
// C = A @ B^T (+bias). 128x128 tile, BK=64, double-buffered swizzled LDS,
// raw s_barrier + vmcnt(8) pipeline. Conflicts measured 0.
template <bool STORE_BF16>
__device__ __forceinline__ void gemm_body(
    const u16* __restrict__ A, const u16* __restrict__ B,
    const float* __restrict__ bias, bool rowbias,
    void* __restrict__ Cout, int ldc, int m0, int n0) {
  constexpr int K = 1024;
  constexpr int NT = K / 64;
  __shared__ __align__(16) u16 As[2][128 * 64];
  __shared__ __align__(16) u16 Bs[2][128 * 64];

  const int t = threadIdx.x;
  const int lane = t & 63;
  const int wv = t >> 6;
  const int quad = lane >> 4;
  const int l15 = lane & 15;
  const int wr = wv >> 1, wc = wv & 1;
  const int sw0 = (quad ^ (l15 & 7)) * 8;
  const int sw1 = ((4 + quad) ^ (l15 & 7)) * 8;

  const f32x4 vzero = {0.f, 0.f, 0.f, 0.f};
  f32x4 acc[4][4];
#pragma unroll
  for (int i = 0; i < 4; ++i)
#pragma unroll
    for (int j = 0; j < 4; ++j) acc[i][j] = vzero;

  auto stage = [&](int kt, int bufi) {
#pragma unroll
    for (int p = 0; p < 4; ++p) {
      int idx = t + p * 256;
      int row = idx >> 3, seg = idx & 7;
      int sseg = seg ^ (row & 7);
      gl_lds16(&A[(long)(m0 + row) * K + kt * 64 + sseg * 8], &As[bufi][idx * 8]);
      gl_lds16(&B[(long)(n0 + row) * K + kt * 64 + sseg * 8], &Bs[bufi][idx * 8]);
    }
  };

  stage(0, 0);
  for (int kt = 0; kt < NT; ++kt) {
    const int bufi = kt & 1;
    if (kt + 1 < NT) {
      stage(kt + 1, bufi ^ 1);
      asm volatile("s_waitcnt vmcnt(8)" ::: "memory");
    } else {
      asm volatile("s_waitcnt vmcnt(0)" ::: "memory");
    }
    asm volatile("s_barrier" ::: "memory");
#pragma unroll
    for (int ks = 0; ks < 64; ks += 32) {
      const int sw = ks ? sw1 : sw0;
      bf16x8 af[4], bfg[4];
#pragma unroll
      for (int i = 0; i < 4; ++i)
        af[i] = *(const bf16x8*)&As[bufi][(wr * 64 + i * 16 + l15) * 64 + sw];
#pragma unroll
      for (int j = 0; j < 4; ++j)
        bfg[j] = *(const bf16x8*)&Bs[bufi][(wc * 64 + j * 16 + l15) * 64 + sw];
#pragma unroll
      for (int i = 0; i < 4; ++i)
#pragma unroll
        for (int j = 0; j < 4; ++j)
          acc[i][j] = __builtin_amdgcn_mfma_f32_16x16x32_bf16(af[i], bfg[j], acc[i][j], 0, 0, 0);
    }
    asm volatile("s_barrier" ::: "memory");
  }

  float cb[4];
  if (!rowbias) {
#pragma unroll
    for (int j = 0; j < 4; ++j) cb[j] = bias[n0 + wc * 64 + j * 16 + l15];
  }

#pragma unroll
  for (int i = 0; i < 4; ++i) {
#pragma unroll
    for (int r = 0; r < 4; ++r) {
      int row = m0 + wr * 64 + i * 16 + quad * 4 + r;
      long base = (long)row * ldc + n0 + wc * 64;
      float rb_ = rowbias ? bias[row] : 0.f;
#pragma unroll
      for (int j = 0; j < 4; ++j) {
        float v = acc[i][j][r] + (rowbias ? rb_ : cb[j]);
        if (STORE_BF16) ((u16*)Cout)[base + j * 16 + l15] = f2bf(v);
        else            ((float*)Cout)[base + j * 16 + l15] = v;
      }
    }
  }
}

// ---------------------------------------------------------------- fused QKV + V^T GEMM
__global__ __launch_bounds__(256) void gemm_qkv(
    const u16* __restrict__ xb, const u16* __restrict__ wqb,
    const u16* __restrict__ wkb, const u16* __restrict__ wvb,
    const float* __restrict__ bq, const float* __restrict__ bk,
    const float* __restrict__ bv,
    u16* __restrict__ Qb, u16* __restrict__ Kb, u16* __restrict__ Vtg) {
  const int bx = blockIdx.x;
  const u16 *AT, *BT;
  const float* bias;
  u16* C;
  int m0, n0, ldc;
  bool rowbias;
  if (bx < 512) {
    int g = bx >> 5;
    int sel = g >> 3;
    n0 = (g & 7) * 128; m0 = (bx & 31) * 128;
    AT = xb; BT = sel ? wkb : wqb; bias = sel ? bk : bq;
    C = sel ? Kb : Qb; ldc = 1024; rowbias = false;
  } else {
    int rem = bx - 512;
    n0 = (rem >> 3) * 128; m0 = (rem & 7) * 128;
    AT = wvb; BT = xb; bias = bv;
    C = Vtg; ldc = 4096; rowbias = true;
  }
  gemm_body<true>(AT, BT, bias, rowbias, C, ldc, m0, n0);
}

// ---------------------------------------------------------------- output GEMM
__global__ __launch_bounds__(256) void gemm_out(
    const u16* __restrict__ A, const u16* __restrict__ B,
    const float* __restrict__ bias, float* __restrict__ C) {
  gemm_body<false>(A, B, bias, false, C, 1024, blockIdx.x * 128, blockIdx.y * 128);
}

// ---------------------------------------------------------------- attention
// 512 threads = 8 waves; block = (b,h, 128-row q-strip). strip = 7 - (bx>>6) (LPT:
// longest chains dispatch first), bh = bx & 63. Wave wv owns q rows
// strip*128 + wv*16 .. +15. Chunks 0..2*strip+1; fast path (const clipped bias,
// mask-free) for c <= 2*strip-2. S^T MFMA + b64 Ws spill + swizzled K/V LDS
// (all mechanisms HW-verified: conflicts = 0). Output in-place over Qb.
__global__ __launch_bounds__(512) void attn_strip(
    const u16* __restrict__ Qb,     // [4096][1024]
    const u16* __restrict__ Kb,     // [4096][1024]
    const u16* __restrict__ Vtg,    // [1024][4096] V^T
    const float* __restrict__ rel_bias,  // [63][16]
    u16* __restrict__ att) {        // == Qb
  constexpr int WS = 68;
  __shared__ __align__(16) u16 Kt[64 * 64];
  __shared__ __align__(16) u16 Vt[64 * 64];
  __shared__ __align__(16) u16 Ws[8][16 * WS];
  __shared__ float biasl[64];

  const int bx = blockIdx.x;
  const int strip = 7 - (bx >> 6);
  const int bh = bx & 63;
  const int b = bh >> 4, h = bh & 15;
  const int q0 = strip * 128;
  const int cend = 2 * strip + 1;

  const int t = threadIdx.x;
  const int lane = t & 63;
  const int wv = t >> 6;          // 0..7
  const int quad = lane >> 4;
  const int l15 = lane & 15;

  if (t < 63) biasl[t] = rel_bias[t * 16 + h];
  const float b0c = rel_bias[h];  // clipped bias for dd <= -31

  // Q fragments: wave's 16 q-rows (A/B-operand layout)
  const long qrow = (long)(b * 1024 + q0 + wv * 16 + l15) * 1024 + h * 64;
  bf16x8 qf0 = *(const bf16x8*)&Qb[qrow + quad * 8];
  bf16x8 qf1 = *(const bf16x8*)&Qb[qrow + 32 + quad * 8];

  const f32x4 vzero = {0.f, 0.f, 0.f, 0.f};
  f32x4 acc_o[4];
#pragma unroll
  for (int j = 0; j < 4; ++j) acc_o[j] = vzero;
  float denom = 0.f;
  const float scale = 0.125f;  // 64^-0.5
  const int ql = q0 + wv * 16 + l15;
  const int sw0 = (quad ^ (l15 & 7)) * 8;
  const int sw1 = ((4 + quad) ^ (l15 & 7)) * 8;

  for (int c = 0; c <= cend; ++c) {
    const int k0 = c * 64;
    if (c) __syncthreads();
    // stage K [key][d] and V^T [d][key]: 512 granules each, 1 per thread
    {
      int row = t >> 3, seg = t & 7;
      int sw = row * 64 + ((seg ^ (row & 7)) * 8);
      uint4 kv = *(const uint4*)&Kb[(long)(b * 1024 + k0 + row) * 1024 + h * 64 + seg * 8];
      uint4 vvl = *(const uint4*)&Vtg[(long)(h * 64 + row) * 4096 + b * 1024 + k0 + seg * 8];
      *(uint4*)&Kt[sw] = kv;
      *(uint4*)&Vt[sw] = vvl;
    }
    __syncthreads();

    const bool fast = (c <= 2 * strip - 2);
#pragma unroll
    for (int g = 0; g < 4; ++g) {
      const u16* kr = &Kt[(g * 16 + l15) * 64];
      bf16x8 kf0 = *(const bf16x8*)&kr[sw0];
      bf16x8 kf1 = *(const bf16x8*)&kr[sw1];
      f32x4 sT = vzero;
      sT = __builtin_amdgcn_mfma_f32_16x16x32_bf16(kf0, qf0, sT, 0, 0, 0);
      sT = __builtin_amdgcn_mfma_f32_16x16x32_bf16(kf1, qf1, sT, 0, 0, 0);
      const int kgb = k0 + g * 16 + quad * 4;
      ushort4 wpk;
      if (fast) {
#pragma unroll
        for (int r = 0; r < 4; ++r) {
          float w = fmaxf(sT[r] * scale + b0c, 0.f) + 1e-6f;
          u16 wb = f2bf(w);
          denom += bf2f(wb);
          ((u16*)&wpk)[r] = wb;
        }
      } else {
#pragma unroll
        for (int r = 0; r < 4; ++r) {
          int kg = kgb + r;
          int dd = kg - ql;
          dd = dd < -31 ? -31 : (dd > 31 ? 31 : dd);
          float sv = sT[r] * scale + biasl[dd + 31];
          float w = (kg <= ql) ? (fmaxf(sv, 0.f) + 1e-6f) : 0.f;
          u16 wb = f2bf(w);
          denom += bf2f(wb);
          ((u16*)&wpk)[r] = wb;
        }
      }
      *(ushort4*)&Ws[wv][l15 * WS + g * 16 + quad * 4] = wpk;
    }
    asm volatile("s_waitcnt lgkmcnt(0)" ::: "memory");   // Ws wave-private W->R
#pragma unroll
    for (int ks = 0; ks < 64; ks += 32) {
      union { bf16x8 v8; bf16x4 v4[2]; } au;
      int wbase = l15 * WS + ks + quad * 8;
      au.v4[0] = *(const bf16x4*)&Ws[wv][wbase];
      au.v4[1] = *(const bf16x4*)&Ws[wv][wbase + 4];
      const int sv = ks ? sw1 : sw0;
#pragma unroll
      for (int j = 0; j < 4; ++j) {
        bf16x8 bvv = *(const bf16x8*)&Vt[(j * 16 + l15) * 64 + sv];
        acc_o[j] = __builtin_amdgcn_mfma_f32_16x16x32_bf16(au.v8, bvv, acc_o[j], 0, 0, 0);
      }
    }
  }

  // denom for q=l15: reduce across the 4 quads
  denom += __shfl_xor(denom, 16);
  denom += __shfl_xor(denom, 32);

  float invm = 1.f / (denom + 1e-6f);
  float inv[4];
#pragma unroll
  for (int r = 0; r < 4; ++r) inv[r] = __shfl(invm, quad * 4 + r);
#pragma unroll
  for (int j = 0; j < 4; ++j)
#pragma unroll
    for (int r = 0; r < 4; ++r) {
      int q = q0 + wv * 16 + quad * 4 + r;
      att[(long)(b * 1024 + q) * 1024 + h * 64 + j * 16 + l15] = f2bf(acc_o[j][r] * inv[r]);
    }
}

// ---------------------------------------------------------------- launch
extern "C" void kernel_launch(void* const* d_in, const int* in_sizes, int n_in,
                              void* d_out, int out_size, void* d_ws, size_t ws_size,
                              hipStream_t stream) {
  const float* x  = (const float*)d_in[0];
  const float* Wq = (const float*)d_in[2];
  const float* bq = (const float*)d_in[3];
  const float* Wk = (const float*)d_in[4];
  const float* bk = (const float*)d_in[5];
  const float* Wv = (const float*)d_in[6];
  const float* bv = (const float*)d_in[7];
  const float* Wo = (const float*)d_in[8];
  const float* bo = (const float*)d_in[9];
  const float* rb = (const float*)d_in[10];

  char* ws = (char*)d_ws;
  u16* xb  = (u16*)(ws);
  u16* wqb = (u16*)(ws + (8l  << 20));
  u16* wkb = (u16*)(ws + (10l << 20));
  u16* wvb = (u16*)(ws + (12l << 20));
  u16* wob = (u16*)(ws + (14l << 20));
  u16* Qb  = (u16*)(ws + (16l << 20));
  u16* Kb  = (u16*)d_out;
  u16* Vtg = (u16*)((char*)d_out + (8l << 20));

  cast_all_kernel<<<8192, 256, 0, stream>>>(x, Wq, Wk, Wv, Wo, xb, wqb, wkb, wvb, wob);
  gemm_qkv<<<768, 256, 0, stream>>>(xb, wqb, wkb, wvb, bq, bk, bv, Qb, Kb, Vtg);
  attn_strip<<<512, 512, 0, stream>>>(Qb, Kb, Vtg, rb, Qb);
  gemm_out<<<dim3(32, 8), 256, 0, stream>>>(Qb, wob, bo, (float*)d_out);
}